// Round 1
// baseline (512.954 us; speedup 1.0000x reference)
//
#include <hip/hip_runtime.h>
#include <hip/hip_bf16.h>

#define N_ 256
#define D_ 64
#define H_ 4
#define DH_ 32
#define EQKV 384
#define EGATE 128
#define NPOS 65536
#define SCALE_F 0.17677669529663687f
#define BIG_NEG -3.402823466e38f

// ws layout (bytes):
//   qkv     bf16 [65536][384]   @ 0          (50331648 B)
//   bias    f32  [4][j=256][i=256] @ 50331648 (1048576 B)
//   gate    f32  [65536][128]   @ 51380224   (33554432 B)
//   attnout f32  [65536][128]   @ 84934656   (33554432 B)
// total 118489088 B (~113 MB)

// ---------------- K1: layernorm + qkv + gate + bias ----------------
__global__ __launch_bounds__(512) void k1_ln_proj(
    const float* __restrict__ z, const float* __restrict__ ln_w, const float* __restrict__ ln_b,
    const float* __restrict__ w_qkv, const float* __restrict__ w_gate, const float* __restrict__ w_bias,
    __hip_bfloat16* __restrict__ qkv_ws, float* __restrict__ gate_ws, float* __restrict__ bias_ws)
{
    __shared__ float h_lds[64][64];
    const int t = threadIdx.x;
    const int wave = t >> 6, lane = t & 63;
    const int pos0 = blockIdx.x * 64;

    const float lw = ln_w[lane], lb = ln_b[lane];
    const float wb0 = w_bias[lane], wb1 = w_bias[64 + lane],
                wb2 = w_bias[128 + lane], wb3 = w_bias[192 + lane];

    // phase A: each wave computes h for 8 positions (lane = d)
    for (int pp = 0; pp < 8; ++pp) {
        const int p = wave * 8 + pp;
        const float zv = z[(size_t)(pos0 + p) * 64 + lane];
        float s = zv, s2 = zv * zv;
        #pragma unroll
        for (int off = 32; off; off >>= 1) { s += __shfl_xor(s, off); s2 += __shfl_xor(s2, off); }
        const float mu = s * 0.015625f;
        const float var = s2 * 0.015625f - mu * mu;
        const float rs = rsqrtf(var + 1e-5f);
        const float hv = (zv - mu) * rs * lw + lb;
        h_lds[p][lane] = hv;
        // bias[h] = sum_d h*w_bias[h][d]
        float b0 = hv * wb0, b1 = hv * wb1, b2 = hv * wb2, b3 = hv * wb3;
        #pragma unroll
        for (int off = 32; off; off >>= 1) {
            b0 += __shfl_xor(b0, off); b1 += __shfl_xor(b1, off);
            b2 += __shfl_xor(b2, off); b3 += __shfl_xor(b3, off);
        }
        if (lane < 4) {
            const int gpos = pos0 + p;
            const int gi = gpos >> 8, gj = gpos & 255;
            const float bv = lane == 0 ? b0 : lane == 1 ? b1 : lane == 2 ? b2 : b3;
            // transposed layout [h][j][i] so K2 reads coalesce over i
            bias_ws[lane * NPOS + gj * 256 + gi] = bv;
        }
    }
    __syncthreads();

    // phase B: thread t = output column e (384 qkv + 128 gate), weights in VGPRs
    const int e = t;
    const float* wcol = (e < EQKV) ? (w_qkv + (size_t)e * 64) : (w_gate + (size_t)(e - EQKV) * 64);
    float4 wr[16];
    #pragma unroll
    for (int c = 0; c < 16; ++c) wr[c] = ((const float4*)wcol)[c];

    for (int p = 0; p < 64; ++p) {
        const float4* h4 = (const float4*)(&h_lds[p][0]);
        float a0 = 0.f, a1 = 0.f, a2 = 0.f, a3 = 0.f;
        #pragma unroll
        for (int c = 0; c < 16; c += 4) {
            float4 x0 = h4[c], x1 = h4[c + 1], x2 = h4[c + 2], x3 = h4[c + 3];
            a0 += x0.x * wr[c].x     + x0.y * wr[c].y     + x0.z * wr[c].z     + x0.w * wr[c].w;
            a1 += x1.x * wr[c + 1].x + x1.y * wr[c + 1].y + x1.z * wr[c + 1].z + x1.w * wr[c + 1].w;
            a2 += x2.x * wr[c + 2].x + x2.y * wr[c + 2].y + x2.z * wr[c + 2].z + x2.w * wr[c + 2].w;
            a3 += x3.x * wr[c + 3].x + x3.y * wr[c + 3].y + x3.z * wr[c + 3].z + x3.w * wr[c + 3].w;
        }
        const float acc = (a0 + a1) + (a2 + a3);
        const int gpos = pos0 + p;
        if (e < EQKV) {
            qkv_ws[(size_t)gpos * EQKV + e] = __float2bfloat16(acc);
        } else {
            gate_ws[(size_t)gpos * EGATE + (e - EQKV)] = 1.0f / (1.0f + __expf(-acc));
        }
    }
}

// ---------------- K2: flash attention per (n, h) ----------------
__global__ __launch_bounds__(256) void k2_attn(
    const __hip_bfloat16* __restrict__ qkv_ws, const float* __restrict__ bias_ws,
    const int* __restrict__ mask, float* __restrict__ attnout_ws)
{
    __shared__ float k_lds[256][32];
    __shared__ float v_lds[256][32];
    __shared__ float keep[256];

    const int n = blockIdx.x >> 2, h = blockIdx.x & 3;
    const int t = threadIdx.x;

    keep[t] = (mask[n * 256 + t] != 0) ? 1.0f : 0.0f;

    // stage k, v (bf16 -> f32). element (j,d): qkv[(n*256+j)*384 + {128,256} + h*32 + d]
    for (int r = 0; r < 16; ++r) {
        const int idx = r * 256 + t;      // 0..4095 bf162 pairs
        const int j = idx >> 4;
        const int d2 = (idx & 15) * 2;
        const size_t base = (size_t)(n * 256 + j) * 384 + h * 32 + d2;
        float2 kf = __bfloat1622float2(*(const __hip_bfloat162*)(qkv_ws + base + 128));
        float2 vf = __bfloat1622float2(*(const __hip_bfloat162*)(qkv_ws + base + 256));
        k_lds[j][d2] = kf.x; k_lds[j][d2 + 1] = kf.y;
        v_lds[j][d2] = vf.x; v_lds[j][d2 + 1] = vf.y;
    }
    __syncthreads();

    // thread = attention row i; online softmax over j
    const int i = t;
    float q[32];
    {
        const __hip_bfloat162* qp = (const __hip_bfloat162*)(qkv_ws + (size_t)(n * 256 + i) * 384 + h * 32);
        #pragma unroll
        for (int d2 = 0; d2 < 16; ++d2) {
            float2 f = __bfloat1622float2(qp[d2]);
            q[2 * d2] = f.x; q[2 * d2 + 1] = f.y;
        }
    }
    const float* brow = bias_ws + (size_t)h * NPOS;  // [j][i]

    float m = -INFINITY, l = 0.f;
    float acc[32];
    #pragma unroll
    for (int d = 0; d < 32; ++d) acc[d] = 0.f;

    for (int j0 = 0; j0 < 256; j0 += 4) {
        float s[4];
        #pragma unroll
        for (int jj = 0; jj < 4; ++jj) {
            const int j = j0 + jj;
            const float4* kr = (const float4*)(&k_lds[j][0]);
            float c0 = 0.f, c1 = 0.f;
            #pragma unroll
            for (int c = 0; c < 8; c += 2) {
                float4 k0 = kr[c], k1 = kr[c + 1];
                c0 += q[4 * c] * k0.x + q[4 * c + 1] * k0.y + q[4 * c + 2] * k0.z + q[4 * c + 3] * k0.w;
                c1 += q[4 * c + 4] * k1.x + q[4 * c + 5] * k1.y + q[4 * c + 6] * k1.z + q[4 * c + 7] * k1.w;
            }
            float sv = (c0 + c1) * SCALE_F + brow[j * 256 + i];
            s[jj] = (keep[j] != 0.f) ? sv : BIG_NEG;
        }
        float mnew = m;
        #pragma unroll
        for (int jj = 0; jj < 4; ++jj) mnew = fmaxf(mnew, s[jj]);
        const float alpha = __expf(m - mnew);
        float p[4]; float psum = 0.f;
        #pragma unroll
        for (int jj = 0; jj < 4; ++jj) { p[jj] = __expf(s[jj] - mnew); psum += p[jj]; }
        l = l * alpha + psum;
        #pragma unroll
        for (int d = 0; d < 32; ++d) acc[d] *= alpha;
        #pragma unroll
        for (int jj = 0; jj < 4; ++jj) {
            const float4* vr = (const float4*)(&v_lds[j0 + jj][0]);
            const float pj = p[jj];
            #pragma unroll
            for (int c = 0; c < 8; ++c) {
                float4 vv = vr[c];
                acc[4 * c]     += pj * vv.x;
                acc[4 * c + 1] += pj * vv.y;
                acc[4 * c + 2] += pj * vv.z;
                acc[4 * c + 3] += pj * vv.w;
            }
        }
        m = mnew;
    }

    const float inv_l = 1.0f / l;
    float* op = attnout_ws + (size_t)(n * 256 + i) * 128 + h * 32;
    #pragma unroll
    for (int d = 0; d < 32; ++d) op[d] = acc[d] * inv_l;
}

// ---------------- K3: out = (attnout * gate) @ w_out^T ----------------
__global__ __launch_bounds__(512) void k3_proj(
    const float* __restrict__ attnout_ws, const float* __restrict__ gate_ws,
    const float* __restrict__ w_out, float* __restrict__ out)
{
    __shared__ float gx[64][128];
    const int t = threadIdx.x;
    const int pos0 = blockIdx.x * 64;

    for (int r = 0; r < 8; ++r) {
        const int idx = r * 512 + t;        // 0..4095 float2 pairs
        const int p = idx >> 6;
        const int c2 = (idx & 63) * 2;
        const size_t g = (size_t)(pos0 + p) * 128 + c2;
        float2 a  = *(const float2*)(attnout_ws + g);
        float2 gt = *(const float2*)(gate_ws + g);
        gx[p][c2] = a.x * gt.x; gx[p][c2 + 1] = a.y * gt.y;
    }
    __syncthreads();

    const int wave = t >> 6, lane = t & 63;
    const int d = (wave & 1) * 32 + (lane & 31);
    const int eh = lane >> 5;               // which e-half this lane sums
    float4 wr[16];
    const float4* wp = (const float4*)(w_out + (size_t)d * 128 + eh * 64);
    #pragma unroll
    for (int c = 0; c < 16; ++c) wr[c] = wp[c];

    const int pg = wave >> 1;               // 4 position groups x 16 positions
    for (int pi = 0; pi < 16; ++pi) {
        const int p = pg * 16 + pi;
        const float4* g4 = (const float4*)(&gx[p][eh * 64]);
        float a0 = 0.f, a1 = 0.f;
        #pragma unroll
        for (int c = 0; c < 16; c += 2) {
            float4 x0 = g4[c], x1 = g4[c + 1];
            a0 += x0.x * wr[c].x + x0.y * wr[c].y + x0.z * wr[c].z + x0.w * wr[c].w;
            a1 += x1.x * wr[c + 1].x + x1.y * wr[c + 1].y + x1.z * wr[c + 1].z + x1.w * wr[c + 1].w;
        }
        float acc = a0 + a1;
        acc += __shfl_xor(acc, 32);
        if (eh == 0) out[(size_t)(pos0 + p) * 64 + d] = acc;
    }
}

extern "C" void kernel_launch(void* const* d_in, const int* in_sizes, int n_in,
                              void* d_out, int out_size, void* d_ws, size_t ws_size,
                              hipStream_t stream) {
    const float* z      = (const float*)d_in[0];
    const int*   mask   = (const int*)d_in[1];
    const float* ln_w   = (const float*)d_in[2];
    const float* ln_b   = (const float*)d_in[3];
    const float* w_qkv  = (const float*)d_in[4];
    const float* w_bias = (const float*)d_in[5];
    const float* w_out  = (const float*)d_in[6];
    const float* w_gate = (const float*)d_in[7];
    float* out = (float*)d_out;

    char* ws = (char*)d_ws;
    __hip_bfloat16* qkv_ws  = (__hip_bfloat16*)(ws);
    float*          bias_ws = (float*)(ws + 50331648);
    float*          gate_ws = (float*)(ws + 51380224);
    float*          attn_ws = (float*)(ws + 84934656);

    k1_ln_proj<<<1024, 512, 0, stream>>>(z, ln_w, ln_b, w_qkv, w_gate, w_bias,
                                         qkv_ws, gate_ws, bias_ws);
    k2_attn<<<1024, 256, 0, stream>>>(qkv_ws, bias_ws, mask, attn_ws);
    k3_proj<<<1024, 512, 0, stream>>>(attn_ws, gate_ws, w_out, out);
}

// Round 2
// 284.647 us; speedup vs baseline: 1.8021x; 1.8021x over previous
//
#include <hip/hip_runtime.h>
#include <hip/hip_bf16.h>

#define N_ 256
#define D_ 64
#define H_ 4
#define DH_ 32
#define EQKV 384
#define EGATE 128
#define NPOS 65536
#define SCALE_F 0.17677669529663687f
#define BIG_NEG -3.402823466e38f
#define P_STRIDE 264   // bf16 elems; 528 B row stride: 16B-aligned, banks spread 4*(m+q)%32

typedef __attribute__((ext_vector_type(8))) short s16x8;
typedef __attribute__((ext_vector_type(4))) float f32x4;

// ws layout (bytes):
//   qkv     bf16 [65536][384]        @ 0          (50331648 B)
//   bias    f32  [4][i=256][j=256]   @ 50331648   (1048576 B)
//   gate    f32  [65536][128]        @ 51380224   (33554432 B)
//   attnout f32  [65536][128]        @ 84934656   (33554432 B)

// ---------------- K1: layernorm + qkv + gate + bias ----------------
__global__ __launch_bounds__(512) void k1_ln_proj(
    const float* __restrict__ z, const float* __restrict__ ln_w, const float* __restrict__ ln_b,
    const float* __restrict__ w_qkv, const float* __restrict__ w_gate, const float* __restrict__ w_bias,
    __hip_bfloat16* __restrict__ qkv_ws, float* __restrict__ gate_ws, float* __restrict__ bias_ws)
{
    __shared__ float h_lds[64][64];
    const int t = threadIdx.x;
    const int wave = t >> 6, lane = t & 63;
    const int pos0 = blockIdx.x * 64;

    const float lw = ln_w[lane], lb = ln_b[lane];
    const float wb0 = w_bias[lane], wb1 = w_bias[64 + lane],
                wb2 = w_bias[128 + lane], wb3 = w_bias[192 + lane];

    for (int pp = 0; pp < 8; ++pp) {
        const int p = wave * 8 + pp;
        const float zv = z[(size_t)(pos0 + p) * 64 + lane];
        float s = zv, s2 = zv * zv;
        #pragma unroll
        for (int off = 32; off; off >>= 1) { s += __shfl_xor(s, off); s2 += __shfl_xor(s2, off); }
        const float mu = s * 0.015625f;
        const float var = s2 * 0.015625f - mu * mu;
        const float rs = rsqrtf(var + 1e-5f);
        const float hv = (zv - mu) * rs * lw + lb;
        h_lds[p][lane] = hv;
        float b0 = hv * wb0, b1 = hv * wb1, b2 = hv * wb2, b3 = hv * wb3;
        #pragma unroll
        for (int off = 32; off; off >>= 1) {
            b0 += __shfl_xor(b0, off); b1 += __shfl_xor(b1, off);
            b2 += __shfl_xor(b2, off); b3 += __shfl_xor(b3, off);
        }
        if (lane < 4) {
            const int gpos = pos0 + p;
            const int gi = gpos >> 8, gj = gpos & 255;
            const float bv = lane == 0 ? b0 : lane == 1 ? b1 : lane == 2 ? b2 : b3;
            // natural layout [h][i][j] so K2 quad-reads over j coalesce
            bias_ws[lane * NPOS + gi * 256 + gj] = bv;
        }
    }
    __syncthreads();

    const int e = t;
    const float* wcol = (e < EQKV) ? (w_qkv + (size_t)e * 64) : (w_gate + (size_t)(e - EQKV) * 64);
    float4 wr[16];
    #pragma unroll
    for (int c = 0; c < 16; ++c) wr[c] = ((const float4*)wcol)[c];

    for (int p = 0; p < 64; ++p) {
        const float4* h4 = (const float4*)(&h_lds[p][0]);
        float a0 = 0.f, a1 = 0.f, a2 = 0.f, a3 = 0.f;
        #pragma unroll
        for (int c = 0; c < 16; c += 4) {
            float4 x0 = h4[c], x1 = h4[c + 1], x2 = h4[c + 2], x3 = h4[c + 3];
            a0 += x0.x * wr[c].x     + x0.y * wr[c].y     + x0.z * wr[c].z     + x0.w * wr[c].w;
            a1 += x1.x * wr[c + 1].x + x1.y * wr[c + 1].y + x1.z * wr[c + 1].z + x1.w * wr[c + 1].w;
            a2 += x2.x * wr[c + 2].x + x2.y * wr[c + 2].y + x2.z * wr[c + 2].z + x2.w * wr[c + 2].w;
            a3 += x3.x * wr[c + 3].x + x3.y * wr[c + 3].y + x3.z * wr[c + 3].z + x3.w * wr[c + 3].w;
        }
        const float acc = (a0 + a1) + (a2 + a3);
        const int gpos = pos0 + p;
        if (e < EQKV) {
            qkv_ws[(size_t)gpos * EQKV + e] = __float2bfloat16(acc);
        } else {
            gate_ws[(size_t)gpos * EGATE + (e - EQKV)] = 1.0f / (1.0f + __expf(-acc));
        }
    }
}

// ---------------- K2: MFMA flash attention ----------------
// grid 4096 = (n:256, h:4, ib:4); block 512 = 8 waves.
// wave (mt = w&3, nh = w>>2): M-tile mt of the 64-row i-block; N-half nh.
__global__ __launch_bounds__(512) void k2_attn_mfma(
    const __hip_bfloat16* __restrict__ qkv_ws, const float* __restrict__ bias_ws,
    const int* __restrict__ mask, float* __restrict__ attnout_ws)
{
    __shared__ short p_s[64 * P_STRIDE];     // P, bf16 bits, [row 0..63][j 0..255]
    __shared__ short vt_s[32 * P_STRIDE];    // V^T, bf16 bits, [d 0..31][j 0..255]
    __shared__ float keep[256];
    __shared__ float redm[64][2];
    __shared__ float redl[64][2];

    const int bx = blockIdx.x;
    const int n = bx >> 4, h = (bx >> 2) & 3, ib = bx & 3;
    const int i0 = ib * 64;
    const int t = threadIdx.x;
    const int wave = t >> 6, lane = t & 63;
    const int m = lane & 15, quad = lane >> 4;
    const int mt = wave & 3, nh = wave >> 2;

    // ---- stage keep + V^T ----
    if (t < 256) keep[t] = (mask[n * 256 + t] != 0) ? 1.0f : 0.0f;
    {
        const int j = t >> 1, dh = (t & 1) * 16;
        const __hip_bfloat16* vp = qkv_ws + (size_t)(n * 256 + j) * 384 + 256 + h * 32 + dh;
        s16x8 v0 = *(const s16x8*)vp;
        s16x8 v1 = *(const s16x8*)(vp + 8);
        #pragma unroll
        for (int e = 0; e < 8; ++e) {
            vt_s[(dh + e) * P_STRIDE + j]     = v0[e];
            vt_s[(dh + 8 + e) * P_STRIDE + j] = v1[e];
        }
    }
    __syncthreads();

    // ---- phase 1: S tiles = Q K^T (MFMA), scale+bias+mask, partial row max ----
    f32x4 s[8];
    {
        const size_t qbase = (size_t)(n * 256 + i0 + mt * 16 + m) * 384 + h * 32 + quad * 8;
        const s16x8 afrag = *(const s16x8*)(qkv_ws + qbase);
        #pragma unroll
        for (int tt = 0; tt < 8; ++tt) {
            const int jt = nh * 8 + tt;
            const size_t kbase = (size_t)(n * 256 + jt * 16 + m) * 384 + 128 + h * 32 + quad * 8;
            const s16x8 bfrag = *(const s16x8*)(qkv_ws + kbase);
            f32x4 z4 = {0.f, 0.f, 0.f, 0.f};
            s[tt] = __builtin_amdgcn_mfma_f32_16x16x32_bf16(afrag, bfrag, z4, 0, 0, 0);
        }
    }
    #pragma unroll
    for (int tt = 0; tt < 8; ++tt) {
        const int j = (nh * 8 + tt) * 16 + m;
        const float kp = keep[j];
        const float* bp = bias_ws + (size_t)h * NPOS + j;
        #pragma unroll
        for (int r = 0; r < 4; ++r) {
            const int irow = i0 + mt * 16 + quad * 4 + r;
            const float sv = s[tt][r] * SCALE_F + bp[irow * 256];
            s[tt][r] = (kp != 0.f) ? sv : BIG_NEG;
        }
    }
    {
        float mp[4];
        #pragma unroll
        for (int r = 0; r < 4; ++r) {
            float v = s[0][r];
            #pragma unroll
            for (int tt = 1; tt < 8; ++tt) v = fmaxf(v, s[tt][r]);
            #pragma unroll
            for (int off = 1; off < 16; off <<= 1) v = fmaxf(v, __shfl_xor(v, off));
            mp[r] = v;
        }
        if (m == 0) {
            #pragma unroll
            for (int r = 0; r < 4; ++r) redm[mt * 16 + quad * 4 + r][nh] = mp[r];
        }
    }
    __syncthreads();

    // ---- phase 2: exp, row sums, write P (bf16) to LDS ----
    {
        float ls[4];
        #pragma unroll
        for (int r = 0; r < 4; ++r) {
            const int row = mt * 16 + quad * 4 + r;
            const float gm = fmaxf(redm[row][0], redm[row][1]);
            float acc = 0.f;
            #pragma unroll
            for (int tt = 0; tt < 8; ++tt) {
                const float p = __expf(s[tt][r] - gm);
                s[tt][r] = p;
                acc += p;
            }
            #pragma unroll
            for (int off = 1; off < 16; off <<= 1) acc += __shfl_xor(acc, off);
            ls[r] = acc;
        }
        if (m == 0) {
            #pragma unroll
            for (int r = 0; r < 4; ++r) redl[mt * 16 + quad * 4 + r][nh] = ls[r];
        }
        #pragma unroll
        for (int tt = 0; tt < 8; ++tt) {
            const int col = (nh * 8 + tt) * 16 + m;
            #pragma unroll
            for (int r = 0; r < 4; ++r) {
                const int row = mt * 16 + quad * 4 + r;
                __hip_bfloat16 pb = __float2bfloat16(s[tt][r]);
                p_s[row * P_STRIDE + col] = *reinterpret_cast<short*>(&pb);
            }
        }
    }
    __syncthreads();

    // ---- phase 3: O = P V via MFMA (A = P rows, B = V^T rows), scale 1/l, store ----
    {
        f32x4 o = {0.f, 0.f, 0.f, 0.f};
        const int arow = mt * 16 + m;     // P row (i within block)
        const int brow = nh * 16 + m;     // V^T row (d)... d < 32 needs nh*16+m < 32 ✓
        #pragma unroll
        for (int kt = 0; kt < 8; ++kt) {
            const s16x8 ap = *(const s16x8*)(p_s + arow * P_STRIDE + kt * 32 + quad * 8);
            const s16x8 bv = *(const s16x8*)(vt_s + brow * P_STRIDE + kt * 32 + quad * 8);
            o = __builtin_amdgcn_mfma_f32_16x16x32_bf16(ap, bv, o, 0, 0, 0);
        }
        #pragma unroll
        for (int r = 0; r < 4; ++r) {
            const int row = mt * 16 + quad * 4 + r;
            const float l = redl[row][0] + redl[row][1];
            const float val = o[r] * (1.0f / l);
            const int ig = i0 + row;
            attnout_ws[(size_t)(n * 256 + ig) * 128 + h * 32 + nh * 16 + m] = val;
        }
    }
}

// ---------------- K3: out = (attnout * gate) @ w_out^T ----------------
__global__ __launch_bounds__(512) void k3_proj(
    const float* __restrict__ attnout_ws, const float* __restrict__ gate_ws,
    const float* __restrict__ w_out, float* __restrict__ out)
{
    __shared__ float gx[64][128];
    const int t = threadIdx.x;
    const int pos0 = blockIdx.x * 64;

    for (int r = 0; r < 8; ++r) {
        const int idx = r * 512 + t;
        const int p = idx >> 6;
        const int c2 = (idx & 63) * 2;
        const size_t g = (size_t)(pos0 + p) * 128 + c2;
        float2 a  = *(const float2*)(attnout_ws + g);
        float2 gt = *(const float2*)(gate_ws + g);
        gx[p][c2] = a.x * gt.x; gx[p][c2 + 1] = a.y * gt.y;
    }
    __syncthreads();

    const int wave = t >> 6, lane = t & 63;
    const int d = (wave & 1) * 32 + (lane & 31);
    const int eh = lane >> 5;
    float4 wr[16];
    const float4* wp = (const float4*)(w_out + (size_t)d * 128 + eh * 64);
    #pragma unroll
    for (int c = 0; c < 16; ++c) wr[c] = wp[c];

    const int pg = wave >> 1;
    for (int pi = 0; pi < 16; ++pi) {
        const int p = pg * 16 + pi;
        const float4* g4 = (const float4*)(&gx[p][eh * 64]);
        float a0 = 0.f, a1 = 0.f;
        #pragma unroll
        for (int c = 0; c < 16; c += 2) {
            float4 x0 = g4[c], x1 = g4[c + 1];
            a0 += x0.x * wr[c].x + x0.y * wr[c].y + x0.z * wr[c].z + x0.w * wr[c].w;
            a1 += x1.x * wr[c + 1].x + x1.y * wr[c + 1].y + x1.z * wr[c + 1].z + x1.w * wr[c + 1].w;
        }
        float acc = a0 + a1;
        acc += __shfl_xor(acc, 32);
        if (eh == 0) out[(size_t)(pos0 + p) * 64 + d] = acc;
    }
}

extern "C" void kernel_launch(void* const* d_in, const int* in_sizes, int n_in,
                              void* d_out, int out_size, void* d_ws, size_t ws_size,
                              hipStream_t stream) {
    const float* z      = (const float*)d_in[0];
    const int*   mask   = (const int*)d_in[1];
    const float* ln_w   = (const float*)d_in[2];
    const float* ln_b   = (const float*)d_in[3];
    const float* w_qkv  = (const float*)d_in[4];
    const float* w_bias = (const float*)d_in[5];
    const float* w_out  = (const float*)d_in[6];
    const float* w_gate = (const float*)d_in[7];
    float* out = (float*)d_out;

    char* ws = (char*)d_ws;
    __hip_bfloat16* qkv_ws  = (__hip_bfloat16*)(ws);
    float*          bias_ws = (float*)(ws + 50331648);
    float*          gate_ws = (float*)(ws + 51380224);
    float*          attn_ws = (float*)(ws + 84934656);

    k1_ln_proj<<<1024, 512, 0, stream>>>(z, ln_w, ln_b, w_qkv, w_gate, w_bias,
                                         qkv_ws, gate_ws, bias_ws);
    k2_attn_mfma<<<4096, 512, 0, stream>>>(qkv_ws, bias_ws, mask, attn_ws);
    k3_proj<<<1024, 512, 0, stream>>>(attn_ws, gate_ws, w_out, out);
}

// Round 3
// 224.668 us; speedup vs baseline: 2.2832x; 1.2670x over previous
//
#include <hip/hip_runtime.h>
#include <hip/hip_bf16.h>

#define N_ 256
#define D_ 64
#define H_ 4
#define DH_ 32
#define EQKV 384
#define EGATE 128
#define NPOS 65536
#define SCALE_F 0.17677669529663687f
#define BIG_NEG -3.402823466e38f
#define P_STRIDE 264   // bf16 elems; 528 B row stride: 16B-aligned, banks (4m+4q)%32 -> 2-way (free)
#define H_STRIDE 72    // K1 h tile stride (bf16): 144 B rows, 16B-aligned, 2-way banks
#define X_STRIDE 136   // K3 x tile stride (bf16): 272 B rows, 16B-aligned, 2-way banks

typedef __attribute__((ext_vector_type(8))) short s16x8;
typedef __attribute__((ext_vector_type(4))) float f32x4;

// ws layout (bytes):
//   qkv     bf16 [65536][384]        @ 0          (50331648 B)
//   bias    f32  [4][i=256][j=256]   @ 50331648   (1048576 B)
//   gate    f32  [65536][128]        @ 51380224   (33554432 B)
//   attnout f32  [65536][128]        @ 84934656   (33554432 B)

__device__ inline short bfbits(float x) {
    __hip_bfloat16 b = __float2bfloat16(x);
    return *reinterpret_cast<short*>(&b);
}
__device__ inline s16x8 cvt8(float4 a, float4 b) {
    s16x8 r;
    r[0] = bfbits(a.x); r[1] = bfbits(a.y); r[2] = bfbits(a.z); r[3] = bfbits(a.w);
    r[4] = bfbits(b.x); r[5] = bfbits(b.y); r[6] = bfbits(b.z); r[7] = bfbits(b.w);
    return r;
}

// ---------------- K1: layernorm + qkv + gate + bias (MFMA) ----------------
// grid 1024 (64 positions each); 8 waves. wave = 64-col slab of N=512 (384 qkv + 128 gate).
__global__ __launch_bounds__(512) void k1_ln_proj_mfma(
    const float* __restrict__ z, const float* __restrict__ ln_w, const float* __restrict__ ln_b,
    const float* __restrict__ w_qkv, const float* __restrict__ w_gate, const float* __restrict__ w_bias,
    __hip_bfloat16* __restrict__ qkv_ws, float* __restrict__ gate_ws, float* __restrict__ bias_ws)
{
    __shared__ short h_bf[64 * H_STRIDE];
    const int t = threadIdx.x;
    const int wave = t >> 6, lane = t & 63;
    const int pos0 = blockIdx.x * 64;
    const int m = lane & 15, quad = lane >> 4;

    // ---- phase A: LN (lane = d), bias from fp32 h, h -> bf16 LDS ----
    {
        const float lw = ln_w[lane], lb = ln_b[lane];
        const float wb0 = w_bias[lane], wb1 = w_bias[64 + lane],
                    wb2 = w_bias[128 + lane], wb3 = w_bias[192 + lane];
        for (int pp = 0; pp < 8; ++pp) {
            const int p = wave * 8 + pp;
            const float zv = z[(size_t)(pos0 + p) * 64 + lane];
            float s = zv, s2 = zv * zv;
            #pragma unroll
            for (int off = 32; off; off >>= 1) { s += __shfl_xor(s, off); s2 += __shfl_xor(s2, off); }
            const float mu = s * 0.015625f;
            const float var = s2 * 0.015625f - mu * mu;
            const float rs = rsqrtf(var + 1e-5f);
            const float hv = (zv - mu) * rs * lw + lb;
            h_bf[p * H_STRIDE + lane] = bfbits(hv);
            float b0 = hv * wb0, b1 = hv * wb1, b2 = hv * wb2, b3 = hv * wb3;
            #pragma unroll
            for (int off = 32; off; off >>= 1) {
                b0 += __shfl_xor(b0, off); b1 += __shfl_xor(b1, off);
                b2 += __shfl_xor(b2, off); b3 += __shfl_xor(b3, off);
            }
            if (lane < 4) {
                const int gpos = pos0 + p;
                const int gi = gpos >> 8, gj = gpos & 255;
                const float bv = lane == 0 ? b0 : lane == 1 ? b1 : lane == 2 ? b2 : b3;
                bias_ws[lane * NPOS + gi * 256 + gj] = bv;   // [h][i][j]
            }
        }
    }
    __syncthreads();

    // ---- phase B: MFMA GEMM, M=64, wave's N-slab=64, K=64 ----
    const int colbase = wave * 64;

    // B-frags from global fp32 weights, converted in-register (L2-resident, 64 KB total)
    s16x8 bfrag[4][2];
    #pragma unroll
    for (int nt = 0; nt < 4; ++nt) {
        const int col = colbase + nt * 16 + m;
        const float* wp = (col < EQKV) ? (w_qkv + (size_t)col * 64)
                                       : (w_gate + (size_t)(col - EQKV) * 64);
        #pragma unroll
        for (int kt = 0; kt < 2; ++kt) {
            const float4 w0 = *(const float4*)(wp + kt * 32 + quad * 8);
            const float4 w1 = *(const float4*)(wp + kt * 32 + quad * 8 + 4);
            bfrag[nt][kt] = cvt8(w0, w1);
        }
    }

    s16x8 afrag[4][2];
    #pragma unroll
    for (int mt = 0; mt < 4; ++mt)
        #pragma unroll
        for (int kt = 0; kt < 2; ++kt)
            afrag[mt][kt] = *(const s16x8*)(h_bf + (mt * 16 + m) * H_STRIDE + kt * 32 + quad * 8);

    f32x4 acc[4][4];
    #pragma unroll
    for (int mt = 0; mt < 4; ++mt)
        #pragma unroll
        for (int nt = 0; nt < 4; ++nt)
            acc[mt][nt] = (f32x4){0.f, 0.f, 0.f, 0.f};

    #pragma unroll
    for (int kt = 0; kt < 2; ++kt)
        #pragma unroll
        for (int mt = 0; mt < 4; ++mt)
            #pragma unroll
            for (int nt = 0; nt < 4; ++nt)
                acc[mt][nt] = __builtin_amdgcn_mfma_f32_16x16x32_bf16(
                    afrag[mt][kt], bfrag[nt][kt], acc[mt][nt], 0, 0, 0);

    // ---- epilogue ----
    if (colbase < EQKV) {
        #pragma unroll
        for (int mt = 0; mt < 4; ++mt)
            #pragma unroll
            for (int nt = 0; nt < 4; ++nt) {
                const int c = colbase + nt * 16 + m;
                #pragma unroll
                for (int r = 0; r < 4; ++r) {
                    const int p = pos0 + mt * 16 + quad * 4 + r;
                    qkv_ws[(size_t)p * EQKV + c] = __float2bfloat16(acc[mt][nt][r]);
                }
            }
    } else {
        #pragma unroll
        for (int mt = 0; mt < 4; ++mt)
            #pragma unroll
            for (int nt = 0; nt < 4; ++nt) {
                const int c = colbase - EQKV + nt * 16 + m;
                #pragma unroll
                for (int r = 0; r < 4; ++r) {
                    const int p = pos0 + mt * 16 + quad * 4 + r;
                    gate_ws[(size_t)p * EGATE + c] = 1.0f / (1.0f + __expf(-acc[mt][nt][r]));
                }
            }
    }
}

// ---------------- K2: MFMA flash attention (unchanged from round 2) ----------------
__global__ __launch_bounds__(512) void k2_attn_mfma(
    const __hip_bfloat16* __restrict__ qkv_ws, const float* __restrict__ bias_ws,
    const int* __restrict__ mask, float* __restrict__ attnout_ws)
{
    __shared__ short p_s[64 * P_STRIDE];
    __shared__ short vt_s[32 * P_STRIDE];
    __shared__ float keep[256];
    __shared__ float redm[64][2];
    __shared__ float redl[64][2];

    const int bx = blockIdx.x;
    const int n = bx >> 4, h = (bx >> 2) & 3, ib = bx & 3;
    const int i0 = ib * 64;
    const int t = threadIdx.x;
    const int wave = t >> 6, lane = t & 63;
    const int m = lane & 15, quad = lane >> 4;
    const int mt = wave & 3, nh = wave >> 2;

    if (t < 256) keep[t] = (mask[n * 256 + t] != 0) ? 1.0f : 0.0f;
    {
        const int j = t >> 1, dh = (t & 1) * 16;
        const __hip_bfloat16* vp = qkv_ws + (size_t)(n * 256 + j) * 384 + 256 + h * 32 + dh;
        s16x8 v0 = *(const s16x8*)vp;
        s16x8 v1 = *(const s16x8*)(vp + 8);
        #pragma unroll
        for (int e = 0; e < 8; ++e) {
            vt_s[(dh + e) * P_STRIDE + j]     = v0[e];
            vt_s[(dh + 8 + e) * P_STRIDE + j] = v1[e];
        }
    }
    __syncthreads();

    f32x4 s[8];
    {
        const size_t qbase = (size_t)(n * 256 + i0 + mt * 16 + m) * 384 + h * 32 + quad * 8;
        const s16x8 afrag = *(const s16x8*)(qkv_ws + qbase);
        #pragma unroll
        for (int tt = 0; tt < 8; ++tt) {
            const int jt = nh * 8 + tt;
            const size_t kbase = (size_t)(n * 256 + jt * 16 + m) * 384 + 128 + h * 32 + quad * 8;
            const s16x8 bfrag = *(const s16x8*)(qkv_ws + kbase);
            f32x4 z4 = {0.f, 0.f, 0.f, 0.f};
            s[tt] = __builtin_amdgcn_mfma_f32_16x16x32_bf16(afrag, bfrag, z4, 0, 0, 0);
        }
    }
    #pragma unroll
    for (int tt = 0; tt < 8; ++tt) {
        const int j = (nh * 8 + tt) * 16 + m;
        const float kp = keep[j];
        const float* bp = bias_ws + (size_t)h * NPOS + j;
        #pragma unroll
        for (int r = 0; r < 4; ++r) {
            const int irow = i0 + mt * 16 + quad * 4 + r;
            const float sv = s[tt][r] * SCALE_F + bp[irow * 256];
            s[tt][r] = (kp != 0.f) ? sv : BIG_NEG;
        }
    }
    {
        float mp[4];
        #pragma unroll
        for (int r = 0; r < 4; ++r) {
            float v = s[0][r];
            #pragma unroll
            for (int tt = 1; tt < 8; ++tt) v = fmaxf(v, s[tt][r]);
            #pragma unroll
            for (int off = 1; off < 16; off <<= 1) v = fmaxf(v, __shfl_xor(v, off));
            mp[r] = v;
        }
        if (m == 0) {
            #pragma unroll
            for (int r = 0; r < 4; ++r) redm[mt * 16 + quad * 4 + r][nh] = mp[r];
        }
    }
    __syncthreads();

    {
        float ls[4];
        #pragma unroll
        for (int r = 0; r < 4; ++r) {
            const int row = mt * 16 + quad * 4 + r;
            const float gm = fmaxf(redm[row][0], redm[row][1]);
            float acc = 0.f;
            #pragma unroll
            for (int tt = 0; tt < 8; ++tt) {
                const float p = __expf(s[tt][r] - gm);
                s[tt][r] = p;
                acc += p;
            }
            #pragma unroll
            for (int off = 1; off < 16; off <<= 1) acc += __shfl_xor(acc, off);
            ls[r] = acc;
        }
        if (m == 0) {
            #pragma unroll
            for (int r = 0; r < 4; ++r) redl[mt * 16 + quad * 4 + r][nh] = ls[r];
        }
        #pragma unroll
        for (int tt = 0; tt < 8; ++tt) {
            const int col = (nh * 8 + tt) * 16 + m;
            #pragma unroll
            for (int r = 0; r < 4; ++r) {
                const int row = mt * 16 + quad * 4 + r;
                p_s[row * P_STRIDE + col] = bfbits(s[tt][r]);
            }
        }
    }
    __syncthreads();

    {
        f32x4 o = {0.f, 0.f, 0.f, 0.f};
        const int arow = mt * 16 + m;
        const int brow = nh * 16 + m;
        #pragma unroll
        for (int kt = 0; kt < 8; ++kt) {
            const s16x8 ap = *(const s16x8*)(p_s + arow * P_STRIDE + kt * 32 + quad * 8);
            const s16x8 bv = *(const s16x8*)(vt_s + brow * P_STRIDE + kt * 32 + quad * 8);
            o = __builtin_amdgcn_mfma_f32_16x16x32_bf16(ap, bv, o, 0, 0, 0);
        }
        #pragma unroll
        for (int r = 0; r < 4; ++r) {
            const int row = mt * 16 + quad * 4 + r;
            const float l = redl[row][0] + redl[row][1];
            const float val = o[r] * (1.0f / l);
            const int ig = i0 + row;
            attnout_ws[(size_t)(n * 256 + ig) * 128 + h * 32 + nh * 16 + m] = val;
        }
    }
}

// ---------------- K3: out = (attnout * gate) @ w_out^T (MFMA) ----------------
// grid 1024 (64 positions); 8 waves = (mt 0..3) x (nh 0..1). N=64, K=128.
__global__ __launch_bounds__(512) void k3_proj_mfma(
    const float* __restrict__ attnout_ws, const float* __restrict__ gate_ws,
    const float* __restrict__ w_out, float* __restrict__ out)
{
    __shared__ short x_bf[64 * X_STRIDE];
    const int t = threadIdx.x;
    const int wave = t >> 6, lane = t & 63;
    const int pos0 = blockIdx.x * 64;
    const int m = lane & 15, quad = lane >> 4;
    const int mt = wave & 3, nh = wave >> 2;

    // stage x = attnout * gate -> bf16 LDS
    #pragma unroll
    for (int r = 0; r < 4; ++r) {
        const int idx = r * 512 + t;          // 2048 float4 groups
        const int p = idx >> 5;
        const int c4 = (idx & 31) * 4;
        const size_t g = (size_t)(pos0 + p) * 128 + c4;
        const float4 a  = *(const float4*)(attnout_ws + g);
        const float4 gt = *(const float4*)(gate_ws + g);
        short4 sv;
        sv.x = bfbits(a.x * gt.x); sv.y = bfbits(a.y * gt.y);
        sv.z = bfbits(a.z * gt.z); sv.w = bfbits(a.w * gt.w);
        *(short4*)(x_bf + p * X_STRIDE + c4) = sv;
    }
    __syncthreads();

    s16x8 bfrag[2][4];
    #pragma unroll
    for (int nt = 0; nt < 2; ++nt) {
        const int d = nh * 32 + nt * 16 + m;
        const float* wp = w_out + (size_t)d * 128;
        #pragma unroll
        for (int kt = 0; kt < 4; ++kt) {
            const float4 w0 = *(const float4*)(wp + kt * 32 + quad * 8);
            const float4 w1 = *(const float4*)(wp + kt * 32 + quad * 8 + 4);
            bfrag[nt][kt] = cvt8(w0, w1);
        }
    }

    s16x8 afrag[4];
    #pragma unroll
    for (int kt = 0; kt < 4; ++kt)
        afrag[kt] = *(const s16x8*)(x_bf + (mt * 16 + m) * X_STRIDE + kt * 32 + quad * 8);

    f32x4 acc[2];
    acc[0] = (f32x4){0.f, 0.f, 0.f, 0.f};
    acc[1] = (f32x4){0.f, 0.f, 0.f, 0.f};
    #pragma unroll
    for (int kt = 0; kt < 4; ++kt) {
        acc[0] = __builtin_amdgcn_mfma_f32_16x16x32_bf16(afrag[kt], bfrag[0][kt], acc[0], 0, 0, 0);
        acc[1] = __builtin_amdgcn_mfma_f32_16x16x32_bf16(afrag[kt], bfrag[1][kt], acc[1], 0, 0, 0);
    }

    #pragma unroll
    for (int nt = 0; nt < 2; ++nt) {
        const int d = nh * 32 + nt * 16 + m;
        #pragma unroll
        for (int r = 0; r < 4; ++r) {
            const int p = pos0 + mt * 16 + quad * 4 + r;
            out[(size_t)p * 64 + d] = acc[nt][r];
        }
    }
}

extern "C" void kernel_launch(void* const* d_in, const int* in_sizes, int n_in,
                              void* d_out, int out_size, void* d_ws, size_t ws_size,
                              hipStream_t stream) {
    const float* z      = (const float*)d_in[0];
    const int*   mask   = (const int*)d_in[1];
    const float* ln_w   = (const float*)d_in[2];
    const float* ln_b   = (const float*)d_in[3];
    const float* w_qkv  = (const float*)d_in[4];
    const float* w_bias = (const float*)d_in[5];
    const float* w_out  = (const float*)d_in[6];
    const float* w_gate = (const float*)d_in[7];
    float* out = (float*)d_out;

    char* ws = (char*)d_ws;
    __hip_bfloat16* qkv_ws  = (__hip_bfloat16*)(ws);
    float*          bias_ws = (float*)(ws + 50331648);
    float*          gate_ws = (float*)(ws + 51380224);
    float*          attn_ws = (float*)(ws + 84934656);

    k1_ln_proj_mfma<<<1024, 512, 0, stream>>>(z, ln_w, ln_b, w_qkv, w_gate, w_bias,
                                              qkv_ws, gate_ws, bias_ws);
    k2_attn_mfma<<<4096, 512, 0, stream>>>(qkv_ws, bias_ws, mask, attn_ws);
    k3_proj_mfma<<<1024, 512, 0, stream>>>(attn_ws, gate_ws, w_out, out);
}

// Round 4
// 206.199 us; speedup vs baseline: 2.4877x; 1.0896x over previous
//
#include <hip/hip_runtime.h>
#include <hip/hip_bf16.h>

#define N_ 256
#define D_ 64
#define H_ 4
#define DH_ 32
#define EQKV 384
#define EGATE 128
#define NPOS 65536
#define SCALE_F 0.17677669529663687f
#define BIG_NEG -3.402823466e38f
#define P_STRIDE 264   // bf16 elems; 528 B rows: 16B-aligned, modest 2-4 way banks
#define H_STRIDE 72    // K1 h tile stride (bf16)
#define X_STRIDE 136   // K3 x tile stride (bf16)

typedef __attribute__((ext_vector_type(8))) short s16x8;
typedef __attribute__((ext_vector_type(4))) float f32x4;

// ws layout (bytes):
//   qkv     bf16 [65536][384]        @ 0          (50331648 B)
//   bias    f32  [4][i=256][j=256]   @ 50331648   (1048576 B)
//   gate    f32  [65536][128]        @ 51380224   (33554432 B)
//   attn    bf16 [65536][128]        @ 84934656   (16777216 B)

__device__ inline short bfbits(float x) {
    __hip_bfloat16 b = __float2bfloat16(x);
    return *reinterpret_cast<short*>(&b);
}
__device__ inline float b2f(short s) {
    unsigned u = ((unsigned)(unsigned short)s) << 16;
    union { unsigned u; float f; } c; c.u = u; return c.f;
}
__device__ inline s16x8 cvt8(float4 a, float4 b) {
    s16x8 r;
    r[0] = bfbits(a.x); r[1] = bfbits(a.y); r[2] = bfbits(a.z); r[3] = bfbits(a.w);
    r[4] = bfbits(b.x); r[5] = bfbits(b.y); r[6] = bfbits(b.z); r[7] = bfbits(b.w);
    return r;
}

// ---------------- K1: layernorm + qkv + gate + bias (MFMA) — unchanged ----------------
__global__ __launch_bounds__(512) void k1_ln_proj_mfma(
    const float* __restrict__ z, const float* __restrict__ ln_w, const float* __restrict__ ln_b,
    const float* __restrict__ w_qkv, const float* __restrict__ w_gate, const float* __restrict__ w_bias,
    __hip_bfloat16* __restrict__ qkv_ws, float* __restrict__ gate_ws, float* __restrict__ bias_ws)
{
    __shared__ short h_bf[64 * H_STRIDE];
    const int t = threadIdx.x;
    const int wave = t >> 6, lane = t & 63;
    const int pos0 = blockIdx.x * 64;
    const int m = lane & 15, quad = lane >> 4;

    {
        const float lw = ln_w[lane], lb = ln_b[lane];
        const float wb0 = w_bias[lane], wb1 = w_bias[64 + lane],
                    wb2 = w_bias[128 + lane], wb3 = w_bias[192 + lane];
        for (int pp = 0; pp < 8; ++pp) {
            const int p = wave * 8 + pp;
            const float zv = z[(size_t)(pos0 + p) * 64 + lane];
            float s = zv, s2 = zv * zv;
            #pragma unroll
            for (int off = 32; off; off >>= 1) { s += __shfl_xor(s, off); s2 += __shfl_xor(s2, off); }
            const float mu = s * 0.015625f;
            const float var = s2 * 0.015625f - mu * mu;
            const float rs = rsqrtf(var + 1e-5f);
            const float hv = (zv - mu) * rs * lw + lb;
            h_bf[p * H_STRIDE + lane] = bfbits(hv);
            float b0 = hv * wb0, b1 = hv * wb1, b2 = hv * wb2, b3 = hv * wb3;
            #pragma unroll
            for (int off = 32; off; off >>= 1) {
                b0 += __shfl_xor(b0, off); b1 += __shfl_xor(b1, off);
                b2 += __shfl_xor(b2, off); b3 += __shfl_xor(b3, off);
            }
            if (lane < 4) {
                const int gpos = pos0 + p;
                const int gi = gpos >> 8, gj = gpos & 255;
                const float bv = lane == 0 ? b0 : lane == 1 ? b1 : lane == 2 ? b2 : b3;
                bias_ws[lane * NPOS + gi * 256 + gj] = bv;   // [h][i][j]
            }
        }
    }
    __syncthreads();

    const int colbase = wave * 64;
    s16x8 bfrag[4][2];
    #pragma unroll
    for (int nt = 0; nt < 4; ++nt) {
        const int col = colbase + nt * 16 + m;
        const float* wp = (col < EQKV) ? (w_qkv + (size_t)col * 64)
                                       : (w_gate + (size_t)(col - EQKV) * 64);
        #pragma unroll
        for (int kt = 0; kt < 2; ++kt) {
            const float4 w0 = *(const float4*)(wp + kt * 32 + quad * 8);
            const float4 w1 = *(const float4*)(wp + kt * 32 + quad * 8 + 4);
            bfrag[nt][kt] = cvt8(w0, w1);
        }
    }

    s16x8 afrag[4][2];
    #pragma unroll
    for (int mt = 0; mt < 4; ++mt)
        #pragma unroll
        for (int kt = 0; kt < 2; ++kt)
            afrag[mt][kt] = *(const s16x8*)(h_bf + (mt * 16 + m) * H_STRIDE + kt * 32 + quad * 8);

    f32x4 acc[4][4];
    #pragma unroll
    for (int mt = 0; mt < 4; ++mt)
        #pragma unroll
        for (int nt = 0; nt < 4; ++nt)
            acc[mt][nt] = (f32x4){0.f, 0.f, 0.f, 0.f};

    #pragma unroll
    for (int kt = 0; kt < 2; ++kt)
        #pragma unroll
        for (int mt = 0; mt < 4; ++mt)
            #pragma unroll
            for (int nt = 0; nt < 4; ++nt)
                acc[mt][nt] = __builtin_amdgcn_mfma_f32_16x16x32_bf16(
                    afrag[mt][kt], bfrag[nt][kt], acc[mt][nt], 0, 0, 0);

    if (colbase < EQKV) {
        #pragma unroll
        for (int mt = 0; mt < 4; ++mt)
            #pragma unroll
            for (int nt = 0; nt < 4; ++nt) {
                const int c = colbase + nt * 16 + m;
                #pragma unroll
                for (int r = 0; r < 4; ++r) {
                    const int p = pos0 + mt * 16 + quad * 4 + r;
                    qkv_ws[(size_t)p * EQKV + c] = __float2bfloat16(acc[mt][nt][r]);
                }
            }
    } else {
        #pragma unroll
        for (int mt = 0; mt < 4; ++mt)
            #pragma unroll
            for (int nt = 0; nt < 4; ++nt) {
                const int c = colbase - EQKV + nt * 16 + m;
                #pragma unroll
                for (int r = 0; r < 4; ++r) {
                    const int p = pos0 + mt * 16 + quad * 4 + r;
                    gate_ws[(size_t)p * EGATE + c] = 1.0f / (1.0f + __expf(-acc[mt][nt][r]));
                }
            }
    }
}

// ---------------- K2: MFMA attention, block = (n,h), 4 i-groups looped ----------------
// grid 1024: n = bx & 255, h = bx >> 8  (same-n blocks land on the same CU sequentially)
__global__ __launch_bounds__(512, 4) void k2_attn_mfma(
    const __hip_bfloat16* __restrict__ qkv_ws, const float* __restrict__ bias_ws,
    const int* __restrict__ mask, __hip_bfloat16* __restrict__ attn_bf)
{
    __shared__ short p_s[64 * P_STRIDE];
    __shared__ short vt_s[32 * P_STRIDE];
    __shared__ float keep[256];
    __shared__ float redm[64][2];
    __shared__ float redl[64][2];

    const int bx = blockIdx.x;
    const int n = bx & 255, h = bx >> 8;
    const int t = threadIdx.x;
    const int wave = t >> 6, lane = t & 63;
    const int m = lane & 15, quad = lane >> 4;
    const int mt = wave & 3, nh = wave >> 2;

    if (t < 256) keep[t] = (mask[n * 256 + t] != 0) ? 1.0f : 0.0f;

    // stage V^T once
    {
        const int j = t >> 1, dh = (t & 1) * 16;
        const __hip_bfloat16* vp = qkv_ws + (size_t)(n * 256 + j) * 384 + 256 + h * 32 + dh;
        s16x8 v0 = *(const s16x8*)vp;
        s16x8 v1 = *(const s16x8*)(vp + 8);
        #pragma unroll
        for (int e = 0; e < 8; ++e) {
            vt_s[(dh + e) * P_STRIDE + j]     = v0[e];
            vt_s[(dh + 8 + e) * P_STRIDE + j] = v1[e];
        }
    }

    // K fragments loaded once, held in registers across all 4 i-groups
    s16x8 kf[8];
    #pragma unroll
    for (int tt = 0; tt < 8; ++tt) {
        const int jt = nh * 8 + tt;
        kf[tt] = *(const s16x8*)(qkv_ws + (size_t)(n * 256 + jt * 16 + m) * 384 + 128 + h * 32 + quad * 8);
    }
    __syncthreads();

    for (int ig = 0; ig < 4; ++ig) {
        const int i0 = ig * 64;

        // ---- phase 1: S = Q K^T, scale+bias+mask, partial row max ----
        f32x4 s[8];
        {
            const size_t qbase = (size_t)(n * 256 + i0 + mt * 16 + m) * 384 + h * 32 + quad * 8;
            const s16x8 afrag = *(const s16x8*)(qkv_ws + qbase);
            #pragma unroll
            for (int tt = 0; tt < 8; ++tt) {
                f32x4 z4 = {0.f, 0.f, 0.f, 0.f};
                s[tt] = __builtin_amdgcn_mfma_f32_16x16x32_bf16(afrag, kf[tt], z4, 0, 0, 0);
            }
        }
        #pragma unroll
        for (int tt = 0; tt < 8; ++tt) {
            const int j = (nh * 8 + tt) * 16 + m;
            const float kp = keep[j];
            const float* bp = bias_ws + (size_t)h * NPOS + j;
            #pragma unroll
            for (int r = 0; r < 4; ++r) {
                const int irow = i0 + mt * 16 + quad * 4 + r;
                const float sv = s[tt][r] * SCALE_F + bp[irow * 256];
                s[tt][r] = (kp != 0.f) ? sv : BIG_NEG;
            }
        }
        {
            float mp[4];
            #pragma unroll
            for (int r = 0; r < 4; ++r) {
                float v = s[0][r];
                #pragma unroll
                for (int tt = 1; tt < 8; ++tt) v = fmaxf(v, s[tt][r]);
                #pragma unroll
                for (int off = 1; off < 16; off <<= 1) v = fmaxf(v, __shfl_xor(v, off));
                mp[r] = v;
            }
            if (m == 0) {
                #pragma unroll
                for (int r = 0; r < 4; ++r) redm[mt * 16 + quad * 4 + r][nh] = mp[r];
            }
        }
        __syncthreads();

        // ---- phase 2: exp, row sums, P (bf16) to LDS ----
        {
            float ls[4];
            #pragma unroll
            for (int r = 0; r < 4; ++r) {
                const int row = mt * 16 + quad * 4 + r;
                const float gm = fmaxf(redm[row][0], redm[row][1]);
                float acc = 0.f;
                #pragma unroll
                for (int tt = 0; tt < 8; ++tt) {
                    const float p = __expf(s[tt][r] - gm);
                    s[tt][r] = p;
                    acc += p;
                }
                #pragma unroll
                for (int off = 1; off < 16; off <<= 1) acc += __shfl_xor(acc, off);
                ls[r] = acc;
            }
            if (m == 0) {
                #pragma unroll
                for (int r = 0; r < 4; ++r) redl[mt * 16 + quad * 4 + r][nh] = ls[r];
            }
            #pragma unroll
            for (int tt = 0; tt < 8; ++tt) {
                const int col = (nh * 8 + tt) * 16 + m;
                #pragma unroll
                for (int r = 0; r < 4; ++r) {
                    const int row = mt * 16 + quad * 4 + r;
                    p_s[row * P_STRIDE + col] = bfbits(s[tt][r]);
                }
            }
        }
        __syncthreads();

        // ---- phase 3: O = P V, scale 1/l, store bf16 ----
        {
            f32x4 o = {0.f, 0.f, 0.f, 0.f};
            const int arow = mt * 16 + m;
            const int brow = nh * 16 + m;
            #pragma unroll
            for (int kt = 0; kt < 8; ++kt) {
                const s16x8 ap = *(const s16x8*)(p_s + arow * P_STRIDE + kt * 32 + quad * 8);
                const s16x8 bv = *(const s16x8*)(vt_s + brow * P_STRIDE + kt * 32 + quad * 8);
                o = __builtin_amdgcn_mfma_f32_16x16x32_bf16(ap, bv, o, 0, 0, 0);
            }
            #pragma unroll
            for (int r = 0; r < 4; ++r) {
                const int row = mt * 16 + quad * 4 + r;
                const float l = redl[row][0] + redl[row][1];
                const float val = o[r] * (1.0f / l);
                const int ig_row = i0 + row;
                attn_bf[(size_t)(n * 256 + ig_row) * 128 + h * 32 + nh * 16 + m] = __float2bfloat16(val);
            }
        }
        __syncthreads();   // protect p_s / redm / redl for next i-group
    }
}

// ---------------- K3: out = (attn_bf * gate) @ w_out^T (MFMA) ----------------
__global__ __launch_bounds__(512) void k3_proj_mfma(
    const __hip_bfloat16* __restrict__ attn_bf, const float* __restrict__ gate_ws,
    const float* __restrict__ w_out, float* __restrict__ out)
{
    __shared__ short x_bf[64 * X_STRIDE];
    const int t = threadIdx.x;
    const int wave = t >> 6, lane = t & 63;
    const int pos0 = blockIdx.x * 64;
    const int m = lane & 15, quad = lane >> 4;
    const int mt = wave & 3, nh = wave >> 2;

    // stage x = attn * gate -> bf16 LDS
    #pragma unroll
    for (int r = 0; r < 4; ++r) {
        const int idx = r * 512 + t;          // 2048 4-elem groups
        const int p = idx >> 5;
        const int c4 = (idx & 31) * 4;
        const size_t g = (size_t)(pos0 + p) * 128 + c4;
        const short4 ab = *(const short4*)(attn_bf + g);
        const float4 gt = *(const float4*)(gate_ws + g);
        short4 sv;
        sv.x = bfbits(b2f(ab.x) * gt.x); sv.y = bfbits(b2f(ab.y) * gt.y);
        sv.z = bfbits(b2f(ab.z) * gt.z); sv.w = bfbits(b2f(ab.w) * gt.w);
        *(short4*)(x_bf + p * X_STRIDE + c4) = sv;
    }
    __syncthreads();

    s16x8 bfrag[2][4];
    #pragma unroll
    for (int nt = 0; nt < 2; ++nt) {
        const int d = nh * 32 + nt * 16 + m;
        const float* wp = w_out + (size_t)d * 128;
        #pragma unroll
        for (int kt = 0; kt < 4; ++kt) {
            const float4 w0 = *(const float4*)(wp + kt * 32 + quad * 8);
            const float4 w1 = *(const float4*)(wp + kt * 32 + quad * 8 + 4);
            bfrag[nt][kt] = cvt8(w0, w1);
        }
    }

    s16x8 afrag[4];
    #pragma unroll
    for (int kt = 0; kt < 4; ++kt)
        afrag[kt] = *(const s16x8*)(x_bf + (mt * 16 + m) * X_STRIDE + kt * 32 + quad * 8);

    f32x4 acc[2];
    acc[0] = (f32x4){0.f, 0.f, 0.f, 0.f};
    acc[1] = (f32x4){0.f, 0.f, 0.f, 0.f};
    #pragma unroll
    for (int kt = 0; kt < 4; ++kt) {
        acc[0] = __builtin_amdgcn_mfma_f32_16x16x32_bf16(afrag[kt], bfrag[0][kt], acc[0], 0, 0, 0);
        acc[1] = __builtin_amdgcn_mfma_f32_16x16x32_bf16(afrag[kt], bfrag[1][kt], acc[1], 0, 0, 0);
    }

    #pragma unroll
    for (int nt = 0; nt < 2; ++nt) {
        const int d = nh * 32 + nt * 16 + m;
        #pragma unroll
        for (int r = 0; r < 4; ++r) {
            const int p = pos0 + mt * 16 + quad * 4 + r;
            out[(size_t)p * 64 + d] = acc[nt][r];
        }
    }
}

extern "C" void kernel_launch(void* const* d_in, const int* in_sizes, int n_in,
                              void* d_out, int out_size, void* d_ws, size_t ws_size,
                              hipStream_t stream) {
    const float* z      = (const float*)d_in[0];
    const int*   mask   = (const int*)d_in[1];
    const float* ln_w   = (const float*)d_in[2];
    const float* ln_b   = (const float*)d_in[3];
    const float* w_qkv  = (const float*)d_in[4];
    const float* w_bias = (const float*)d_in[5];
    const float* w_out  = (const float*)d_in[6];
    const float* w_gate = (const float*)d_in[7];
    float* out = (float*)d_out;

    char* ws = (char*)d_ws;
    __hip_bfloat16* qkv_ws  = (__hip_bfloat16*)(ws);
    float*          bias_ws = (float*)(ws + 50331648);
    float*          gate_ws = (float*)(ws + 51380224);
    __hip_bfloat16* attn_bf = (__hip_bfloat16*)(ws + 84934656);

    k1_ln_proj_mfma<<<1024, 512, 0, stream>>>(z, ln_w, ln_b, w_qkv, w_gate, w_bias,
                                              qkv_ws, gate_ws, bias_ws);
    k2_attn_mfma<<<1024, 512, 0, stream>>>(qkv_ws, bias_ws, mask, attn_bf);
    k3_proj_mfma<<<1024, 512, 0, stream>>>(attn_bf, gate_ws, w_out, out);
}